// Round 11
// baseline (396.901 us; speedup 1.0000x reference)
//
#include <hip/hip_runtime.h>

// RF grid-sample DAS beamforming.
// Shapes: d_tx[4,512,256] d_rx[128,512,256] apod[128,512,256] rf[4,128,3072] t0[4]
// out[4,512,256] fp32.
//
// R11: cross-block TLP. Ladder: R0=93 (2x512thr blocks, lockstep, starved).
// R8=83.5 (DMA double-buffer, 1 barrier, 8 waves). R9=69.4 (TPB=1024 +
// stream-reg prefetch, 16 waves, VGPR 52). R10=78 (fp16-dup via reg staging:
// conflicts halved AGAIN exactly, but staging VALU/VMEM cost > LDS savings —
// falsified as a lever at this structure).
// R9 analysis: 10.4k cyc/iter ~= VALU 5.5k + LDS 5.5k SUMMED, not overlapped
// -> intra-block latency bubbles at 4 waves/SIMD. Fix: 2 blocks/CU.
//  - Single 48KB fp32 buffer (not 96KB dbuf) -> 2 blocks/CU -> 32 waves/CU
//    (8/SIMD, HW max). DMA-wait inside a block (2 barriers/iter) is covered
//    by the co-resident block's compute.
//  - ESPLIT 16: grid 32x16=512 = exactly 2/CU. Consecutive blocks share
//    grid.y -> same rf rows -> 2nd block's DMA L2-hits.
//  - __launch_bounds__(1024,2) pins VGPR<=64 (R9 measured 52 with identical
//    live state; headroom real).
//  - Keeps: async DMA rf staging (zero VGPR), stream drx/ap prefetch into
//    regs (compute phase has zero global deps), lane-contiguous stride-TPB
//    addressing for streams + atomics (R6 lesson), fp32 LDS (R7/R10 lesson).
// Litmus: VGPR<=64, FETCH ~91MB, WRITE ~33MB; occupancy 70%+.
// Partial sums across 16 e-chunks via fp32 atomicAdd (out zeroed by memset;
// graph-capture safe).
// Data range: delay in [0,3070] => i1 <= 3071 = S-1: clamp is no-op safety.

#define A_N 4
#define E_N 128
#define S_N 3072
#define NPIX_N (512 * 256)
#define TPB 1024                   // threads per block (16 waves)
#define PXT 4                      // pixels per thread (stride-TPB)
#define TILE (TPB * PXT)           // 4096 pixels per block
#define TILES (NPIX_N / TILE)      // 32
#define ESPLIT 16                  // e-chunks
#define EPB (E_N / ESPLIT)         // 8 elements per block
#define CPA (S_N / 256)            // 12 1KB-chunks per angle row
#define CHUNKS (A_N * CPA)         // 48 chunks per buffer
#define WAVES (TPB / 64)           // 16
#define CPW (CHUNKS / WAVES)       // 3 chunks per wave

__device__ __forceinline__ void ld_lds16(const float* g, float* l) {
    // 64 lanes x 16B: global (per-lane addr) -> LDS (wave-uniform base,
    // HW adds lane*16). size must be a literal 16.
    __builtin_amdgcn_global_load_lds(
        (const __attribute__((address_space(1))) void*)g,
        (__attribute__((address_space(3))) void*)l, 16, 0, 0);
}

__global__ __launch_bounds__(TPB, 2) void das_kernel(
    const float* __restrict__ d_tx, const float* __restrict__ d_rx,
    const float* __restrict__ apod, const float* __restrict__ rf,
    const float* __restrict__ t0,  float* __restrict__ out)
{
    __shared__ float lds_rf[A_N * S_N];   // 48 KB single buffer
    const int tid  = threadIdx.x;
    const int wid  = tid >> 6;
    const int lane = tid & 63;
    const int px0  = blockIdx.x * TILE + tid;   // + k*TPB for k in [0,PXT)
    const int e0   = blockIdx.y * EPB;

    // Issue async DMA of rf[a][e][:] (all 4 angles, 48KB).
    auto stage = [&](int e) {
#pragma unroll
        for (int j = 0; j < CPW; ++j) {
            const int chunk = wid * CPW + j;        // 0..47, wave-uniform
            const int a = chunk / CPA;              // 0..3
            const int c = chunk - a * CPA;          // 0..11
            const float* g = rf + ((size_t)(a * E_N + e)) * S_N + c * 256 + lane * 4;
            float* l = &lds_rf[a * S_N + c * 256];
            ld_lds16(g, l);
        }
    };

    stage(e0);   // prologue DMA starts immediately

    float acc[A_N][PXT];
    float dta[A_N][PXT];
#pragma unroll
    for (int a = 0; a < A_N; ++a) {
        const float t0a = t0[a];
#pragma unroll
        for (int k = 0; k < PXT; ++k) {
            dta[a][k] = d_tx[a * NPIX_N + px0 + k * TPB] - t0a;
            acc[a][k] = 0.0f;
        }
    }

    // Prologue stream loads for ei=0.
    float ndrx[PXT], nap[PXT];
#pragma unroll
    for (int k = 0; k < PXT; ++k) {
        ndrx[k] = d_rx[(size_t)e0 * NPIX_N + px0 + k * TPB];
        nap[k]  = apod[(size_t)e0 * NPIX_N + px0 + k * TPB];
    }

    __syncthreads();   // drains vmcnt: prologue DMA + streams complete

    for (int ei = 0; ei < EPB; ++ei) {
        const int e = e0 + ei;

        // Current iteration's stream values (loaded last iteration).
        float drx[PXT], ap[PXT];
#pragma unroll
        for (int k = 0; k < PXT; ++k) { drx[k] = ndrx[k]; ap[k] = nap[k]; }

        // Prefetch next iteration's stream values; latency hides under interp.
        if (ei + 1 < EPB) {
            const float* __restrict__ nd = d_rx + (size_t)(e + 1) * NPIX_N;
            const float* __restrict__ na = apod + (size_t)(e + 1) * NPIX_N;
#pragma unroll
            for (int k = 0; k < PXT; ++k) {
                ndrx[k] = nd[px0 + k * TPB];
                nap[k]  = na[px0 + k * TPB];
            }
        }

        // Interp: zero global-memory dependencies (LDS + VALU only).
#pragma unroll
        for (int k = 0; k < PXT; ++k) {
#pragma unroll
            for (int a = 0; a < A_N; ++a) {
                float delay = dta[a][k] + drx[k];
                float x0 = floorf(delay);
                float w  = delay - x0;
                int i0 = (int)x0;
                i0 = min(max(i0, 0), S_N - 2);   // no-op for this data; safety
                float v0 = lds_rf[a * S_N + i0];
                float v1 = lds_rf[a * S_N + i0 + 1];
                acc[a][k] += (v0 + w * (v1 - v0)) * ap[k];
            }
        }

        if (ei + 1 < EPB) {
            __syncthreads();      // all gathers done: buffer free for refill
            stage(e + 1);         // async DMA refill
            __syncthreads();      // implicit vmcnt(0): DMA complete.
            // The DMA-wait gap here is covered by the co-resident block's
            // compute phase (2 blocks/CU, phases anti-align).
        }
    }

#pragma unroll
    for (int a = 0; a < A_N; ++a)
#pragma unroll
        for (int k = 0; k < PXT; ++k)
            atomicAdd(&out[a * NPIX_N + px0 + k * TPB], acc[a][k]);
}

extern "C" void kernel_launch(void* const* d_in, const int* in_sizes, int n_in,
                              void* d_out, int out_size, void* d_ws, size_t ws_size,
                              hipStream_t stream) {
    const float* d_tx = (const float*)d_in[0];
    const float* d_rx = (const float*)d_in[1];
    const float* apod = (const float*)d_in[2];
    const float* rf   = (const float*)d_in[3];
    const float* t0   = (const float*)d_in[4];
    float* out = (float*)d_out;

    hipMemsetAsync(out, 0, (size_t)out_size * sizeof(float), stream);
    dim3 grid(TILES, ESPLIT);
    das_kernel<<<grid, TPB, 0, stream>>>(d_tx, d_rx, apod, rf, t0, out);
}